// Round 1
// baseline (158.907 us; speedup 1.0000x reference)
//
#include <hip/hip_runtime.h>
#include <math.h>

#define NROWS 65536
#define FDIM 64
#define EDIM 16
#define NH1 8
#define NH2 4
#define BN_EPS 1e-5f

// ---- workspace layout (floats) ----
// [0, N)                 : partial[n]  (fm_first part without xc_mean term + fm_second_mean)
// [N, 9N)                : h[n*8+j]
// [9N, +1024)            : U = W1+W2
// +512 each              : A1, A2, A3   (A[f*8+j])
// +96*512                : per-block partials, transposed: blkT[v*512 + blk]
//                          v: 0..63 = Xc colsum, 64..71 = sum h_j, 72..79 = sum h_j^2
// +96                    : reduced totals T[v]
#define OFF_PARTIAL 0
#define OFF_H       65536
#define OFF_U       589824
#define OFF_A1      590848
#define OFF_A2      591360
#define OFF_A3      591872
#define OFF_BLKT    592384
#define OFF_T       641536

__global__ __launch_bounds__(256) void precompute_kernel(
    const float* __restrict__ W1, const float* __restrict__ B1,
    const float* __restrict__ W2, const float* __restrict__ B2,
    const float* __restrict__ lin1_w,
    float* __restrict__ U, float* __restrict__ A1,
    float* __restrict__ A2, float* __restrict__ A3)
{
    __shared__ __align__(16) float sU[1024];
    int tid = threadIdx.x;
    for (int i = tid; i < 1024; i += 256) {
        float u = W1[i] + W2[i];
        sU[i] = u;
        U[i] = u;
    }
    __syncthreads();
    for (int p = tid; p < 512; p += 256) {
        int f = p >> 3, j = p & 7;
        const float* lw = lin1_w + j * 1024 + f * 16;
        float a1 = 0.f, a2 = 0.f, a3 = 0.f;
#pragma unroll
        for (int e = 0; e < 16; e++) {
            float lwv = lw[e];
            a1 = fmaf(sU[f * 16 + e], lwv, a1);
            a2 = fmaf(B1[f * 16 + e], lwv, a2);
            a3 = fmaf(B2[f * 16 + e], lwv, a3);
        }
        A1[p] = a1; A2[p] = a2; A3[p] = a3;
    }
}

// 512 blocks x 256 threads. Block handles 128 rows; 2 threads per row (f halves).
__global__ __launch_bounds__(256) void main_kernel(
    const float* __restrict__ Xa, const float* __restrict__ Xc,
    const float* __restrict__ w1, const float* __restrict__ b1,
    const float* __restrict__ b2, const float* __restrict__ lin1_b,
    const float* __restrict__ gU, const float* __restrict__ gA1,
    const float* __restrict__ gA2, const float* __restrict__ gA3,
    const float* __restrict__ gB1, const float* __restrict__ gB2,
    float* __restrict__ ws_partial, float* __restrict__ ws_h,
    float* __restrict__ ws_blkT)
{
    __shared__ __align__(16) float sU[1024];
    __shared__ __align__(16) float sB1[1024];
    __shared__ __align__(16) float sB2[1024];
    __shared__ __align__(16) float sA1[512];
    __shared__ __align__(16) float sA2[512];
    __shared__ __align__(16) float sA3[512];
    __shared__ float sw1[64], sb1v[64], sb2v[64], slb[8];
    __shared__ float scol[256];
    __shared__ float sred[64];

    int tid = threadIdx.x;
    int blk = blockIdx.x;
    int rowbase = blk * 128;

    // load small weights into LDS
    for (int i = tid; i < 1024; i += 256) {
        sU[i]  = gU[i];
        sB1[i] = gB1[i];
        sB2[i] = gB2[i];
    }
    for (int i = tid; i < 512; i += 256) {
        sA1[i] = gA1[i];
        sA2[i] = gA2[i];
        sA3[i] = gA3[i];
    }
    if (tid < 64) { sw1[tid] = w1[tid]; sb1v[tid] = b1[tid]; sb2v[tid] = b2[tid]; }
    if (tid < 8)  slb[tid] = lin1_b[tid];

    // phase 1: coalesced Xc column sums over this block's 128 rows
    {
        int col = tid & 63, grp = tid >> 6;
        float acc = 0.f;
        for (int r = grp; r < 128; r += 4)
            acc += Xc[(rowbase + r) * 64 + col];
        scol[tid] = acc;
    }
    __syncthreads();
    if (tid < 64) {
        float t = scol[tid] + scol[64 + tid] + scol[128 + tid] + scol[192 + tid];
        ws_blkT[tid * 512 + blk] = t;
    }

    // phase 2: per-row compute, 2 threads/row
    int half = tid & 1;
    int row = rowbase + (tid >> 1);
    int f0 = half * 32;
    const float4* xa4 = (const float4*)(Xa + row * 64 + f0);
    const float4* xc4 = (const float4*)(Xc + row * 64 + f0);

    float s[16];
    float qs[16];
    float hh[8];
#pragma unroll
    for (int e = 0; e < 16; e++) { s[e] = 0.f; qs[e] = 0.f; }
#pragma unroll
    for (int j = 0; j < 8; j++) hh[j] = 0.f;
    float p1 = 0.f, p2a = 0.f;

#pragma unroll
    for (int k = 0; k < 8; k++) {
        float4 av = xa4[k];
        float4 cv = xc4[k];
        float af[4] = {av.x, av.y, av.z, av.w};
        float cf[4] = {cv.x, cv.y, cv.z, cv.w};
#pragma unroll
        for (int u = 0; u < 4; u++) {
            int f = f0 + k * 4 + u;
            float a = af[u], c = cf[u];
            float pp = a * c;
            p1 += (sw1[f] * a + sb1v[f]) * c;
            p2a = fmaf(a, sb2v[f], p2a);
            const float4* Uf  = (const float4*)(sU  + f * 16);
            const float4* B1f = (const float4*)(sB1 + f * 16);
            const float4* B2f = (const float4*)(sB2 + f * 16);
#pragma unroll
            for (int e4 = 0; e4 < 4; e4++) {
                float4 uu = Uf[e4], bb = B1f[e4], cc = B2f[e4];
                float t0 = pp * uu.x + c * bb.x + a * cc.x;
                float t1 = pp * uu.y + c * bb.y + a * cc.y;
                float t2 = pp * uu.z + c * bb.z + a * cc.z;
                float t3 = pp * uu.w + c * bb.w + a * cc.w;
                int e = e4 * 4;
                s[e]     += t0; s[e + 1] += t1; s[e + 2] += t2; s[e + 3] += t3;
                qs[e]     = fmaf(t0, t0, qs[e]);
                qs[e + 1] = fmaf(t1, t1, qs[e + 1]);
                qs[e + 2] = fmaf(t2, t2, qs[e + 2]);
                qs[e + 3] = fmaf(t3, t3, qs[e + 3]);
            }
            float4 a1lo = *(const float4*)(sA1 + f * 8);
            float4 a1hi = *(const float4*)(sA1 + f * 8 + 4);
            float4 a2lo = *(const float4*)(sA2 + f * 8);
            float4 a2hi = *(const float4*)(sA2 + f * 8 + 4);
            float4 a3lo = *(const float4*)(sA3 + f * 8);
            float4 a3hi = *(const float4*)(sA3 + f * 8 + 4);
            hh[0] += pp * a1lo.x + c * a2lo.x + a * a3lo.x;
            hh[1] += pp * a1lo.y + c * a2lo.y + a * a3lo.y;
            hh[2] += pp * a1lo.z + c * a2lo.z + a * a3lo.z;
            hh[3] += pp * a1lo.w + c * a2lo.w + a * a3lo.w;
            hh[4] += pp * a1hi.x + c * a2hi.x + a * a3hi.x;
            hh[5] += pp * a1hi.y + c * a2hi.y + a * a3hi.y;
            hh[6] += pp * a1hi.z + c * a2hi.z + a * a3hi.z;
            hh[7] += pp * a1hi.w + c * a2hi.w + a * a3hi.w;
        }
    }

    // combine the two f-halves (lane pairs 2i / 2i+1)
#pragma unroll
    for (int e = 0; e < 16; e++) {
        s[e]  += __shfl_xor(s[e], 1);
        qs[e] += __shfl_xor(qs[e], 1);
    }
#pragma unroll
    for (int j = 0; j < 8; j++) hh[j] += __shfl_xor(hh[j], 1);
    p1  += __shfl_xor(p1, 1);
    p2a += __shfl_xor(p2a, 1);

#pragma unroll
    for (int j = 0; j < 8; j++) hh[j] += slb[j];

    float fm2 = 0.f;
#pragma unroll
    for (int e = 0; e < 16; e++) fm2 += s[e] * s[e] - qs[e];
    fm2 *= 0.5f / 16.f;
    float partial = (p1 + p2a) * (1.f / 64.f) + fm2;

    if (!half) {
        ws_partial[row] = partial;
        float4 h0 = make_float4(hh[0], hh[1], hh[2], hh[3]);
        float4 h1 = make_float4(hh[4], hh[5], hh[6], hh[7]);
        *(float4*)(ws_h + row * 8)     = h0;
        *(float4*)(ws_h + row * 8 + 4) = h1;
    }

    // BN partial sums: count each row once (half==0 lanes)
    float v[16];
#pragma unroll
    for (int j = 0; j < 8; j++) {
        v[j]     = half ? 0.f : hh[j];
        v[8 + j] = half ? 0.f : hh[j] * hh[j];
    }
#pragma unroll
    for (int off = 1; off < 64; off <<= 1) {
#pragma unroll
        for (int i = 0; i < 16; i++) v[i] += __shfl_xor(v[i], off);
    }
    int lane = tid & 63, wid = tid >> 6;
    if (lane == 0) {
#pragma unroll
        for (int i = 0; i < 16; i++) sred[wid * 16 + i] = v[i];
    }
    __syncthreads();
    if (tid < 16) {
        float t = sred[tid] + sred[16 + tid] + sred[32 + tid] + sred[48 + tid];
        ws_blkT[(64 + tid) * 512 + blk] = t;
    }
}

// 96 waves: one per statistic; reduce 512 block-partials each.
__global__ __launch_bounds__(256) void reduce_kernel(
    const float* __restrict__ ws_blkT, float* __restrict__ T)
{
    int gtid = blockIdx.x * 256 + threadIdx.x;
    int v = gtid >> 6;
    int lane = gtid & 63;
    if (v < 96) {
        const float* p = ws_blkT + v * 512 + lane;
        float acc = 0.f;
#pragma unroll
        for (int k = 0; k < 8; k++) acc += p[k * 64];
#pragma unroll
        for (int off = 32; off; off >>= 1) acc += __shfl_xor(acc, off);
        if (lane == 0) T[v] = acc;
    }
}

// 256 blocks x 256 threads: one row per thread.
__global__ __launch_bounds__(256) void final_kernel(
    const float* __restrict__ Xa, const float* __restrict__ w2,
    const float* __restrict__ gamma, const float* __restrict__ beta,
    const float* __restrict__ lin2_w, const float* __restrict__ lin2_b,
    const float* __restrict__ T, const float* __restrict__ ws_partial,
    const float* __restrict__ ws_h, float* __restrict__ out)
{
    __shared__ float sg[64], sscale[8], sshift[8], sl2w[32], sl2b[4];
    int tid = threadIdx.x;
    if (tid < 64) {
        sg[tid] = w2[tid] * (T[tid] * (1.f / 65536.f));
    } else if (tid < 72) {
        int j = tid - 64;
        float mu  = T[64 + j] * (1.f / 65536.f);
        float var = T[72 + j] * (1.f / 65536.f) - mu * mu;
        float sc = gamma[j] / sqrtf(var + BN_EPS);
        sscale[j] = sc;
        sshift[j] = beta[j] - mu * sc;
    } else if (tid < 104) {
        sl2w[tid - 72] = lin2_w[tid - 72];
    } else if (tid < 108) {
        sl2b[tid - 104] = lin2_b[tid - 104];
    }
    __syncthreads();

    int row = blockIdx.x * 256 + tid;
    const float4* xa4 = (const float4*)(Xa + row * 64);
    float p2b = 0.f;
#pragma unroll
    for (int k = 0; k < 16; k++) {
        float4 vv = xa4[k];
        p2b += vv.x * sg[k * 4] + vv.y * sg[k * 4 + 1]
             + vv.z * sg[k * 4 + 2] + vv.w * sg[k * 4 + 3];
    }
    float4 h0 = *(const float4*)(ws_h + row * 8);
    float4 h1 = *(const float4*)(ws_h + row * 8 + 4);
    float hv[8] = {h0.x, h0.y, h0.z, h0.w, h1.x, h1.y, h1.z, h1.w};
    float hn[8];
#pragma unroll
    for (int j = 0; j < 8; j++)
        hn[j] = tanhf(hv[j] * sscale[j] + sshift[j]);
    float dm = 0.f;
#pragma unroll
    for (int k2 = 0; k2 < 4; k2++) {
        float o = sl2b[k2];
#pragma unroll
        for (int j = 0; j < 8; j++) o = fmaf(hn[j], sl2w[k2 * 8 + j], o);
        dm += o;
    }
    out[row] = ws_partial[row] + p2b * (1.f / 64.f) + dm * 0.25f;
}

extern "C" void kernel_launch(void* const* d_in, const int* in_sizes, int n_in,
                              void* d_out, int out_size, void* d_ws, size_t ws_size,
                              hipStream_t stream) {
    const float* Xa       = (const float*)d_in[0];
    const float* Xc       = (const float*)d_in[1];
    const float* w1       = (const float*)d_in[2];
    const float* b1       = (const float*)d_in[3];
    const float* w2       = (const float*)d_in[4];
    const float* b2       = (const float*)d_in[5];
    const float* W1       = (const float*)d_in[6];
    const float* B1       = (const float*)d_in[7];
    const float* W2       = (const float*)d_in[8];
    const float* B2       = (const float*)d_in[9];
    const float* lin1_w   = (const float*)d_in[10];
    const float* lin1_b   = (const float*)d_in[11];
    const float* bn1_gamma= (const float*)d_in[12];
    const float* bn1_beta = (const float*)d_in[13];
    const float* lin2_w   = (const float*)d_in[14];
    const float* lin2_b   = (const float*)d_in[15];

    float* ws = (float*)d_ws;
    float* out = (float*)d_out;

    float* ws_partial = ws + OFF_PARTIAL;
    float* ws_h       = ws + OFF_H;
    float* ws_U       = ws + OFF_U;
    float* ws_A1      = ws + OFF_A1;
    float* ws_A2      = ws + OFF_A2;
    float* ws_A3      = ws + OFF_A3;
    float* ws_blkT    = ws + OFF_BLKT;
    float* ws_T       = ws + OFF_T;

    precompute_kernel<<<1, 256, 0, stream>>>(W1, B1, W2, B2, lin1_w,
                                             ws_U, ws_A1, ws_A2, ws_A3);
    main_kernel<<<512, 256, 0, stream>>>(Xa, Xc, w1, b1, b2, lin1_b,
                                         ws_U, ws_A1, ws_A2, ws_A3, B1, B2,
                                         ws_partial, ws_h, ws_blkT);
    reduce_kernel<<<24, 256, 0, stream>>>(ws_blkT, ws_T);
    final_kernel<<<256, 256, 0, stream>>>(Xa, w2, bn1_gamma, bn1_beta,
                                          lin2_w, lin2_b, ws_T,
                                          ws_partial, ws_h, out);
}

// Round 2
// 151.431 us; speedup vs baseline: 1.0494x; 1.0494x over previous
//
#include <hip/hip_runtime.h>
#include <math.h>

#define NROWS 65536
#define BN_EPS 1e-5f

// ---- workspace layout (floats) ----
// OFF_PARTIAL : per-row partial (fm_first w/o xc_mean term + fm_second_mean)   [65536]
// OFF_H       : h[row*8+j]                                                      [524288]
// OFF_REC     : packed per-feature record rec[f][84]                            [5376]
//               0..15 U=W1+W2 | 16..31 B1 | 32..47 B2 | 48..55 A1 | 56..63 A2
//               64..71 A3 | 72 QU 73 QB1 74 QB2 75 2QUB1 76 2QUB2 77 2QB1B2
//               78 w1 79 b1 80 b2 | 81..83 pad
// OFF_BLKT    : per-block partials transposed blkT[v*1024+blk], v<80            [98304]
//               v 0..63 Xc colsum, 64..71 sum h_j, 72..79 sum h_j^2
// OFF_T       : reduced totals                                                  [96]
#define OFF_PARTIAL 0
#define OFF_H       65536
#define OFF_REC     589824
#define OFF_BLKT    595200
#define OFF_T       693504

__global__ __launch_bounds__(256) void precompute_kernel(
    const float* __restrict__ W1, const float* __restrict__ B1,
    const float* __restrict__ W2, const float* __restrict__ B2,
    const float* __restrict__ lin1_w, const float* __restrict__ w1,
    const float* __restrict__ b1, const float* __restrict__ b2,
    float* __restrict__ rec)
{
    __shared__ float sU[1024], sB1[1024], sB2[1024];
    int tid = threadIdx.x;
    for (int i = tid; i < 1024; i += 256) {
        float u = W1[i] + W2[i];
        float x = B1[i], y = B2[i];
        sU[i] = u; sB1[i] = x; sB2[i] = y;
        int f = i >> 4, e = i & 15;
        rec[f * 84 + e]      = u;
        rec[f * 84 + 16 + e] = x;
        rec[f * 84 + 32 + e] = y;
    }
    __syncthreads();
    for (int p = tid; p < 512; p += 256) {
        int f = p >> 3, j = p & 7;
        const float* lw = lin1_w + j * 1024 + f * 16;
        float a1 = 0.f, a2 = 0.f, a3 = 0.f;
#pragma unroll
        for (int e = 0; e < 16; e++) {
            float lwv = lw[e];
            a1 = fmaf(sU[f * 16 + e], lwv, a1);
            a2 = fmaf(sB1[f * 16 + e], lwv, a2);
            a3 = fmaf(sB2[f * 16 + e], lwv, a3);
        }
        rec[f * 84 + 48 + j] = a1;
        rec[f * 84 + 56 + j] = a2;
        rec[f * 84 + 64 + j] = a3;
    }
    if (tid < 64) {
        int f = tid;
        float qu = 0.f, qb1 = 0.f, qb2 = 0.f, qub1 = 0.f, qub2 = 0.f, qb12 = 0.f;
#pragma unroll
        for (int e = 0; e < 16; e++) {
            float u = sU[f * 16 + e], x = sB1[f * 16 + e], y = sB2[f * 16 + e];
            qu   = fmaf(u, u, qu);
            qb1  = fmaf(x, x, qb1);
            qb2  = fmaf(y, y, qb2);
            qub1 = fmaf(u, x, qub1);
            qub2 = fmaf(u, y, qub2);
            qb12 = fmaf(x, y, qb12);
        }
        rec[f * 84 + 72] = qu;
        rec[f * 84 + 73] = qb1;
        rec[f * 84 + 74] = qb2;
        rec[f * 84 + 75] = 2.f * qub1;
        rec[f * 84 + 76] = 2.f * qub2;
        rec[f * 84 + 77] = 2.f * qb12;
        rec[f * 84 + 78] = w1[f];
        rec[f * 84 + 79] = b1[f];
        rec[f * 84 + 80] = b2[f];
    }
}

// 1024 blocks x 256 threads. Block = 64 rows; wave w handles f-quarter w for
// all 64 rows (lane = row). Table reads are wave-uniform -> scalar (SMEM) pipe.
__global__ __launch_bounds__(256, 4) void main_kernel(
    const float* __restrict__ Xa, const float* __restrict__ Xc,
    const float* __restrict__ rec, const float* __restrict__ lin1_b,
    float* __restrict__ ws_partial, float* __restrict__ ws_h,
    float* __restrict__ ws_blkT)
{
    __shared__ float cmb[4][64][29];  // stride 29: conflict-free

    int tid  = threadIdx.x;
    int lane = tid & 63;
    int wv   = tid >> 6;
    int wu   = __builtin_amdgcn_readfirstlane(wv);  // force SGPR -> scalar loads
    int blk  = blockIdx.x;
    int row  = blk * 64 + lane;
    int f0   = wu * 16;

    const float4* pa = (const float4*)(Xa + (size_t)row * 64 + f0);
    const float4* pc = (const float4*)(Xc + (size_t)row * 64 + f0);
    float a_[16], c_[16];
#pragma unroll
    for (int k = 0; k < 4; k++) {
        float4 av = pa[k], cv = pc[k];
        a_[k * 4] = av.x; a_[k * 4 + 1] = av.y; a_[k * 4 + 2] = av.z; a_[k * 4 + 3] = av.w;
        c_[k * 4] = cv.x; c_[k * 4 + 1] = cv.y; c_[k * 4 + 2] = cv.z; c_[k * 4 + 3] = cv.w;
    }

    float s[16], hh[8];
#pragma unroll
    for (int e = 0; e < 16; e++) s[e] = 0.f;
#pragma unroll
    for (int j = 0; j < 8; j++) hh[j] = 0.f;
    float p1 = 0.f, p2a = 0.f, qsum = 0.f;

    const float* recw = rec + (size_t)f0 * 84;
#pragma unroll
    for (int i = 0; i < 16; i++) {
        const float* r = recw + i * 84;   // uniform address -> s_load
        float a = a_[i], c = c_[i];
        float pp = a * c;
        p1  = fmaf(fmaf(r[78], a, r[79]), c, p1);
        p2a = fmaf(a, r[80], p2a);
        qsum = fmaf(pp * pp, r[72], qsum);
        qsum = fmaf(c * c,   r[73], qsum);
        qsum = fmaf(a * a,   r[74], qsum);
        qsum = fmaf(pp * c,  r[75], qsum);
        qsum = fmaf(pp * a,  r[76], qsum);
        qsum = fmaf(pp,      r[77], qsum);
#pragma unroll
        for (int e = 0; e < 16; e++)
            s[e] = fmaf(pp, r[e], fmaf(c, r[16 + e], fmaf(a, r[32 + e], s[e])));
#pragma unroll
        for (int j = 0; j < 8; j++)
            hh[j] = fmaf(pp, r[48 + j], fmaf(c, r[56 + j], fmaf(a, r[64 + j], hh[j])));
    }

    // Xc column sums for this block (reduce c_ over the 64 lanes = rows)
    {
        float cs[16];
#pragma unroll
        for (int i = 0; i < 16; i++) cs[i] = c_[i];
#pragma unroll
        for (int off = 1; off < 64; off <<= 1) {
#pragma unroll
            for (int i = 0; i < 16; i++) cs[i] += __shfl_xor(cs[i], off);
        }
        if (lane == 0) {
#pragma unroll
            for (int i = 0; i < 16; i++)
                ws_blkT[(size_t)(f0 + i) * 1024 + blk] = cs[i];
        }
    }

    // stash per-wave partials for cross-wave combine
#pragma unroll
    for (int e = 0; e < 16; e++) cmb[wv][lane][e] = s[e];
#pragma unroll
    for (int j = 0; j < 8; j++) cmb[wv][lane][16 + j] = hh[j];
    cmb[wv][lane][24] = p1;
    cmb[wv][lane][25] = p2a;
    cmb[wv][lane][26] = qsum;
    __syncthreads();

    if (tid < 64) {
        float S[16], H[8], P1 = 0.f, P2 = 0.f, Q = 0.f;
#pragma unroll
        for (int e = 0; e < 16; e++) S[e] = 0.f;
#pragma unroll
        for (int j = 0; j < 8; j++) H[j] = 0.f;
#pragma unroll
        for (int w = 0; w < 4; w++) {
#pragma unroll
            for (int e = 0; e < 16; e++) S[e] += cmb[w][tid][e];
#pragma unroll
            for (int j = 0; j < 8; j++) H[j] += cmb[w][tid][16 + j];
            P1 += cmb[w][tid][24];
            P2 += cmb[w][tid][25];
            Q  += cmb[w][tid][26];
        }
#pragma unroll
        for (int j = 0; j < 8; j++) H[j] += lin1_b[j];

        float ss = 0.f;
#pragma unroll
        for (int e = 0; e < 16; e++) ss = fmaf(S[e], S[e], ss);
        float fm2 = (ss - Q) * (0.5f / 16.f);
        int rr = blk * 64 + tid;
        ws_partial[rr] = (P1 + P2) * (1.f / 64.f) + fm2;
        *(float4*)(ws_h + (size_t)rr * 8)     = make_float4(H[0], H[1], H[2], H[3]);
        *(float4*)(ws_h + (size_t)rr * 8 + 4) = make_float4(H[4], H[5], H[6], H[7]);

        // BN partials over this block's 64 rows (single wave)
        float v[16];
#pragma unroll
        for (int j = 0; j < 8; j++) { v[j] = H[j]; v[8 + j] = H[j] * H[j]; }
#pragma unroll
        for (int off = 1; off < 64; off <<= 1) {
#pragma unroll
            for (int i = 0; i < 16; i++) v[i] += __shfl_xor(v[i], off);
        }
        if (tid == 0) {
#pragma unroll
            for (int i = 0; i < 16; i++)
                ws_blkT[(size_t)(64 + i) * 1024 + blk] = v[i];
        }
    }
}

// 80 waves: one per statistic; reduce 1024 block-partials each.
__global__ __launch_bounds__(256) void reduce_kernel(
    const float* __restrict__ ws_blkT, float* __restrict__ T)
{
    int gtid = blockIdx.x * 256 + threadIdx.x;
    int v = gtid >> 6;
    int lane = gtid & 63;
    const float* p = ws_blkT + (size_t)v * 1024 + lane;
    float acc = 0.f;
#pragma unroll
    for (int k = 0; k < 16; k++) acc += p[k * 64];
#pragma unroll
    for (int off = 32; off; off >>= 1) acc += __shfl_xor(acc, off);
    if (lane == 0) T[v] = acc;
}

// 512 blocks x 128 threads: one row per thread.
__global__ __launch_bounds__(128) void final_kernel(
    const float* __restrict__ Xa, const float* __restrict__ w2,
    const float* __restrict__ gamma, const float* __restrict__ beta,
    const float* __restrict__ lin2_w, const float* __restrict__ lin2_b,
    const float* __restrict__ T, const float* __restrict__ ws_partial,
    const float* __restrict__ ws_h, float* __restrict__ out)
{
    __shared__ float sg[64], sscale[8], sshift[8], sl2w[32], sl2b[4];
    int tid = threadIdx.x;
    if (tid < 64) {
        sg[tid] = w2[tid] * (T[tid] * (1.f / 65536.f));
    } else if (tid < 72) {
        int j = tid - 64;
        float mu  = T[64 + j] * (1.f / 65536.f);
        float var = T[72 + j] * (1.f / 65536.f) - mu * mu;
        float sc = gamma[j] / sqrtf(var + BN_EPS);
        sscale[j] = sc;
        sshift[j] = beta[j] - mu * sc;
    } else if (tid < 104) {
        sl2w[tid - 72] = lin2_w[tid - 72];
    } else if (tid < 108) {
        sl2b[tid - 104] = lin2_b[tid - 104];
    }
    __syncthreads();

    int row = blockIdx.x * 128 + tid;
    const float4* xa4 = (const float4*)(Xa + (size_t)row * 64);
    float p2b = 0.f;
#pragma unroll
    for (int k = 0; k < 16; k++) {
        float4 vv = xa4[k];
        p2b += vv.x * sg[k * 4] + vv.y * sg[k * 4 + 1]
             + vv.z * sg[k * 4 + 2] + vv.w * sg[k * 4 + 3];
    }
    float4 h0 = *(const float4*)(ws_h + (size_t)row * 8);
    float4 h1 = *(const float4*)(ws_h + (size_t)row * 8 + 4);
    float hv[8] = {h0.x, h0.y, h0.z, h0.w, h1.x, h1.y, h1.z, h1.w};
    float hn[8];
#pragma unroll
    for (int j = 0; j < 8; j++)
        hn[j] = tanhf(hv[j] * sscale[j] + sshift[j]);
    float dm = 0.f;
#pragma unroll
    for (int k2 = 0; k2 < 4; k2++) {
        float o = sl2b[k2];
#pragma unroll
        for (int j = 0; j < 8; j++) o = fmaf(hn[j], sl2w[k2 * 8 + j], o);
        dm += o;
    }
    out[row] = ws_partial[row] + p2b * (1.f / 64.f) + dm * 0.25f;
}

extern "C" void kernel_launch(void* const* d_in, const int* in_sizes, int n_in,
                              void* d_out, int out_size, void* d_ws, size_t ws_size,
                              hipStream_t stream) {
    const float* Xa        = (const float*)d_in[0];
    const float* Xc        = (const float*)d_in[1];
    const float* w1        = (const float*)d_in[2];
    const float* b1        = (const float*)d_in[3];
    const float* w2        = (const float*)d_in[4];
    const float* b2        = (const float*)d_in[5];
    const float* W1        = (const float*)d_in[6];
    const float* B1        = (const float*)d_in[7];
    const float* W2        = (const float*)d_in[8];
    const float* B2        = (const float*)d_in[9];
    const float* lin1_w    = (const float*)d_in[10];
    const float* lin1_b    = (const float*)d_in[11];
    const float* bn1_gamma = (const float*)d_in[12];
    const float* bn1_beta  = (const float*)d_in[13];
    const float* lin2_w    = (const float*)d_in[14];
    const float* lin2_b    = (const float*)d_in[15];

    float* ws  = (float*)d_ws;
    float* out = (float*)d_out;

    float* ws_partial = ws + OFF_PARTIAL;
    float* ws_h       = ws + OFF_H;
    float* ws_rec     = ws + OFF_REC;
    float* ws_blkT    = ws + OFF_BLKT;
    float* ws_T       = ws + OFF_T;

    precompute_kernel<<<1, 256, 0, stream>>>(W1, B1, W2, B2, lin1_w,
                                             w1, b1, b2, ws_rec);
    main_kernel<<<1024, 256, 0, stream>>>(Xa, Xc, ws_rec, lin1_b,
                                          ws_partial, ws_h, ws_blkT);
    reduce_kernel<<<20, 256, 0, stream>>>(ws_blkT, ws_T);
    final_kernel<<<512, 128, 0, stream>>>(Xa, w2, bn1_gamma, bn1_beta,
                                          lin2_w, lin2_b, ws_T,
                                          ws_partial, ws_h, out);
}